// Round 1
// baseline (613.394 us; speedup 1.0000x reference)
//
#include <hip/hip_runtime.h>

// CIF (continuous integrate-and-fire) timestamp kernel.
// B=4096 independent rows, T=8192 sequential steps per row.
// Must be BIT-EXACT vs the numpy sequential reference:
//   s = fl32(acc + a); fire = s; acc = (s >= 1.0f) ? s - 1.0f : s;
// Since acc,a in [0,1), s in [0,2): the reset is exactly fract(s)
// (Sterbenz: s-1 exact for s in [1,2)).
//
// K1: full-row scan (acc only), records chunk-boundary accs -> d_ws,
//     final acc -> integrate_new.  Latency-bound on the dependent chain.
// K2: replays each 1024-step chunk from its bit-exact boundary acc,
//     writes fires.  BW-bound.
//
// LDS layout is TRANSPOSED [col][row] with row-stride 65 so the compute
// wave's per-step read (64 lanes = 64 rows, same col) is a contiguous
// 64-float run -> conflict-free (2 lanes/bank).

constexpr int Bn    = 4096;
constexpr int Tn    = 8192;
constexpr int NCH   = 8;
constexpr int CHUNK = Tn / NCH;     // 1024

__device__ __forceinline__ float cif_fract(float s){
#if __has_builtin(__builtin_amdgcn_fractf)
    return __builtin_amdgcn_fractf(s);   // s - floor(s): exact for s in [0,2)
#else
    return s - floorf(s);
#endif
}

// ----------------------------- Kernel 1 ------------------------------------
constexpr int K1_ROWS = 64;
constexpr int K1_C    = 64;               // cols per tile
constexpr int K1_NT   = Tn / K1_C;        // 128 tiles
constexpr int K1_STR  = K1_ROWS + 1;      // 65 (pad: transposed scalar writes)

__global__ __launch_bounds__(256)
void cif_k1_boundaries(const float* __restrict__ A,
                       const float* __restrict__ integ,
                       float* __restrict__ bnd,       // [B][NCH]
                       float* __restrict__ out_int)   // d_out + B*T
{
    __shared__ float lds[2][K1_C][K1_STR];            // 2 * 64*65*4 = 33.3 KB
    const int tid     = threadIdx.x;
    const int rowbase = blockIdx.x * K1_ROWS;

    // per-tile: 64 rows * 16 float4 = 1024 float4, transposed into LDS
    auto load_tile = [&](int it, int bf, int tbase, int nthr){
        const float4* src = (const float4*)A;
        for (int q = tid - tbase; q < K1_ROWS * (K1_C / 4); q += nthr){
            int r  = q >> 4;
            int c4 = q & 15;
            float4 v = src[((size_t)(rowbase + r) * Tn + (size_t)it * K1_C) / 4 + c4];
            int c = c4 * 4;
            lds[bf][c + 0][r] = v.x;
            lds[bf][c + 1][r] = v.y;
            lds[bf][c + 2][r] = v.z;
            lds[bf][c + 3][r] = v.w;
        }
    };

    load_tile(0, 0, 0, 256);              // prologue: all threads
    __syncthreads();

    float acc = 0.f;
    if (tid < 64) acc = integ[rowbase + tid];

    for (int it = 0; it < K1_NT; ++it){
        const int bf = it & 1;
        if (tid < 64){
            // chunk boundary: acc BEFORE processing col it*K1_C
            if ((it & (CHUNK / K1_C - 1)) == 0)
                bnd[(size_t)(rowbase + tid) * NCH + (it / (CHUNK / K1_C))] = acc;
            #pragma unroll
            for (int c = 0; c < K1_C; ++c){
                float s = acc + lds[bf][c][tid];
                acc = cif_fract(s);
            }
        } else if (it + 1 < K1_NT){
            load_tile(it + 1, bf ^ 1, 64, 192);   // waves 1-3 prefetch
        }
        __syncthreads();
    }
    if (tid < 64) out_int[rowbase + tid] = acc;
}

// ----------------------------- Kernel 2 ------------------------------------
constexpr int K2_ROWS = 64;
constexpr int K2_C    = 128;              // cols per tile
constexpr int K2_STR  = K2_ROWS + 1;      // 65
constexpr int K2_NT   = CHUNK / K2_C;     // 8 tiles per chunk

__global__ __launch_bounds__(256)
void cif_k2_fires(const float* __restrict__ A,
                  const float* __restrict__ bnd,
                  float* __restrict__ fires)
{
    __shared__ float lds[K2_C][K2_STR];   // 33.3 KB
    const int tid     = threadIdx.x;
    const int chunk   = blockIdx.x;                  // 0..7
    const int rowbase = blockIdx.y * K2_ROWS;
    const size_t colbase = (size_t)chunk * CHUNK;

    float acc = 0.f;
    if (tid < 64) acc = bnd[(size_t)(rowbase + tid) * NCH + chunk];

    for (int t = 0; t < K2_NT; ++t){
        {   // coalesced load, transposed into LDS
            const float4* src = (const float4*)A;
            for (int q = tid; q < K2_ROWS * (K2_C / 4); q += 256){
                int r  = q >> 5;
                int c4 = q & 31;
                float4 v = src[((size_t)(rowbase + r) * Tn + colbase + (size_t)t * K2_C) / 4 + c4];
                int c = c4 * 4;
                lds[c + 0][r] = v.x;
                lds[c + 1][r] = v.y;
                lds[c + 2][r] = v.z;
                lds[c + 3][r] = v.w;
            }
        }
        __syncthreads();
        if (tid < 64){
            #pragma unroll
            for (int c = 0; c < K2_C; ++c){
                float s = acc + lds[c][tid];
                lds[c][tid] = s;                     // fire value, in place
                acc = cif_fract(s);
            }
        }
        __syncthreads();
        {   // coalesced store of fires
            float4* dst = (float4*)fires;
            for (int q = tid; q < K2_ROWS * (K2_C / 4); q += 256){
                int r  = q >> 5;
                int c4 = q & 31;
                int c  = c4 * 4;
                float4 v;
                v.x = lds[c + 0][r];
                v.y = lds[c + 1][r];
                v.z = lds[c + 2][r];
                v.w = lds[c + 3][r];
                dst[((size_t)(rowbase + r) * Tn + colbase + (size_t)t * K2_C) / 4 + c4] = v;
            }
        }
        __syncthreads();   // safety: store-reads vs next-iter LDS writes
    }
}

// ----------------------------- Launch --------------------------------------
extern "C" void kernel_launch(void* const* d_in, const int* in_sizes, int n_in,
                              void* d_out, int out_size, void* d_ws, size_t ws_size,
                              hipStream_t stream)
{
    const float* A     = (const float*)d_in[0];   // us_alphas [B][T]
    const float* integ = (const float*)d_in[1];   // integrate [B]
    float* out   = (float*)d_out;                 // fires [B*T] ++ integrate_new [B]
    float* bnd   = (float*)d_ws;                  // [B][NCH] = 128 KB scratch

    hipLaunchKernelGGL(cif_k1_boundaries,
                       dim3(Bn / K1_ROWS), dim3(256), 0, stream,
                       A, integ, bnd, out + (size_t)Bn * Tn);

    hipLaunchKernelGGL(cif_k2_fires,
                       dim3(NCH, Bn / K2_ROWS), dim3(256), 0, stream,
                       A, bnd, out);
}

// Round 3
// 300.376 us; speedup vs baseline: 2.0421x; 2.0421x over previous
//
#include <hip/hip_runtime.h>

// CIF (continuous integrate-and-fire), single fused pass.
// B=4096 independent rows, T=8192 sequential steps per row.
// Bit-exact vs reference:  s = fl32(acc + a); fire = s;
//                          acc = (s>=1) ? s-1 : s  ==  fract(s)  (exact, s in [0,2))
//
// Structure: 512 blocks x 256 threads, 8 rows per block (2 blocks/CU).
//   per tile (8 rows x 256 cols = 8KB):
//     1. all threads issue next tile's 2 float4 loads into regs (latency hides
//        under compute)
//     2. lanes 0-7 run the 256-step dependent chain from the transposed LDS
//        tile, writing fires in-place
//     3. barrier; all threads store fires coalesced; write staged regs to the
//        other LDS buffer (compiler waits vmcnt on the loads only); barrier.
// LDS [col][row] stride 9: compute reads conflict-free, transposed scalar
// writes/reads are uniform 2-way (free). Mandatory HBM traffic 268MB -> 43us floor.

constexpr int Bn   = 4096;
constexpr int Tn   = 8192;
constexpr int R    = 8;          // rows per block
constexpr int C    = 256;        // cols per tile
constexpr int S    = R + 1;      // padded stride (9)
constexpr int NIT  = Tn / C;     // 32 tiles
constexpr int NBLK = Bn / R;     // 512 blocks

__device__ __forceinline__ float cif_fract(float s){
#if __has_builtin(__builtin_amdgcn_fractf)
    return __builtin_amdgcn_fractf(s);   // s - floor(s): exact for s in [0,2)
#else
    return s - floorf(s);
#endif
}

__global__ __launch_bounds__(256)
void cif_fused(const float* __restrict__ A,
               const float* __restrict__ integ,
               float* __restrict__ fires,      // d_out
               float* __restrict__ out_int)    // d_out + B*T
{
    __shared__ float lds[2][C][S];
    const int tid     = threadIdx.x;
    const int rowbase = blockIdx.x * R;

    // staging decomposition: thread -> (row r, f4-columns c4a, c4a+32)
    // tid bits 3-5 -> r, bits 0-2 & 6-7 -> c4a. Wave w covers 8 rows x 128B.
    const int r   = (tid >> 3) & (R - 1);
    const int c4a = (tid & 7) + 8 * (tid >> 6);   // 0..31
    const int c4b = c4a + 32;                     // 32..63

    const float4* __restrict__ src = (const float4*)A + (size_t)(rowbase + r) * (Tn / 4);
    float4* __restrict__       dst = (float4*)fires   + (size_t)(rowbase + r) * (Tn / 4);

    auto write_tile = [&](int bf, const float4& a, const float4& b){
        const int ca = 4 * c4a, cb = 4 * c4b;
        lds[bf][ca + 0][r] = a.x;
        lds[bf][ca + 1][r] = a.y;
        lds[bf][ca + 2][r] = a.z;
        lds[bf][ca + 3][r] = a.w;
        lds[bf][cb + 0][r] = b.x;
        lds[bf][cb + 1][r] = b.y;
        lds[bf][cb + 2][r] = b.z;
        lds[bf][cb + 3][r] = b.w;
    };

    // prologue: stage tile 0
    {
        float4 a = src[c4a];
        float4 b = src[c4b];
        write_tile(0, a, b);
    }
    float acc = (tid < R) ? integ[rowbase + tid] : 0.f;
    __syncthreads();

    for (int it = 0; it < NIT; ++it){
        const int bf = it & 1;

        // 1. issue next tile's loads early (complete during compute phase)
        float4 pa, pb;
        const bool pf = (it + 1 < NIT);
        if (pf){
            pa = src[(it + 1) * (C / 4) + c4a];
            pb = src[(it + 1) * (C / 4) + c4b];
        }

        // 2. sequential integrate-and-fire over this tile, fires in-place
        if (tid < R){
            #pragma unroll
            for (int c = 0; c < C; ++c){
                float s = acc + lds[bf][c][tid];
                lds[bf][c][tid] = s;            // fire value (pre-reset)
                acc = cif_fract(s);
            }
        }
        __syncthreads();                         // fires visible to all waves

        // 3a. coalesced fires store (reads lds[bf]; writes don't block)
        {
            const int ca = 4 * c4a, cb = 4 * c4b;
            float4 w0, w1;
            w0.x = lds[bf][ca + 0][r]; w0.y = lds[bf][ca + 1][r];
            w0.z = lds[bf][ca + 2][r]; w0.w = lds[bf][ca + 3][r];
            w1.x = lds[bf][cb + 0][r]; w1.y = lds[bf][cb + 1][r];
            w1.z = lds[bf][cb + 2][r]; w1.w = lds[bf][cb + 3][r];
            dst[it * (C / 4) + c4a] = w0;
            dst[it * (C / 4) + c4b] = w1;
        }

        // 3b. write staged regs into the other buffer (waits vmcnt on loads only)
        if (pf)
            write_tile(bf ^ 1, pa, pb);

        __syncthreads();                         // next tile ready
    }

    if (tid < R) out_int[rowbase + tid] = acc;
}

// ----------------------------- Launch --------------------------------------
extern "C" void kernel_launch(void* const* d_in, const int* in_sizes, int n_in,
                              void* d_out, int out_size, void* d_ws, size_t ws_size,
                              hipStream_t stream)
{
    const float* A     = (const float*)d_in[0];   // us_alphas [B][T]
    const float* integ = (const float*)d_in[1];   // integrate [B]
    float* out = (float*)d_out;                   // fires [B*T] ++ integrate_new [B]

    hipLaunchKernelGGL(cif_fused, dim3(NBLK), dim3(256), 0, stream,
                       A, integ, out, out + (size_t)Bn * Tn);
}

// Round 4
// 251.407 us; speedup vs baseline: 2.4398x; 1.1948x over previous
//
#include <hip/hip_runtime.h>

// CIF (continuous integrate-and-fire), fused single pass, v2.
// Bit-exact vs reference: s = fl32(acc + a); fire = s; acc = fract(s)
// (exact for s in [0,2): Sterbenz).
//
// Structure: 256 blocks x 320 threads (5 waves), 16 rows per block (1 block/CU).
//   LDS tile: row-major [16 rows][128 cols + 4 pad] (row stride 528B, 16B
//   aligned, (4r+c)%32 bank pattern => all accesses uniform/2-way = free).
//   Ring of 3 buffers, one barrier per tile:
//     wave 0  : lane l computes row l's 128-step chain: ds_read_b128 (4 cols),
//               4x(add+fract), write fires back in place (ds_write_b128).
//     waves1-4: store fires of tile k-1 (LDS->global f4, coalesced),
//               stage tile k+1 (global f4 -> LDS direct, no transpose).
// Chain per block = 8192*8cyc = 27us, hidden under the 268MB/6.3TB/s = 43us
// BW floor spread over all 256 CUs.

constexpr int Bn   = 4096;
constexpr int Tn   = 8192;
constexpr int R    = 16;          // rows (chains) per block
constexpr int C    = 128;         // cols per tile
constexpr int LSTR = C + 4;       // 132 floats = 528B row stride (16B aligned)
constexpr int NT   = Tn / C;      // 64 tiles
constexpr int NBLK = Bn / R;      // 256 blocks
constexpr int NTHR = 320;         // 5 waves

__device__ __forceinline__ float cif_fract(float s){
#if __has_builtin(__builtin_amdgcn_fractf)
    return __builtin_amdgcn_fractf(s);   // v_fract_f32: s - floor(s), exact
#else
    return s - floorf(s);
#endif
}

__global__ __launch_bounds__(NTHR)
void cif_fused(const float* __restrict__ A,
               const float* __restrict__ integ,
               float* __restrict__ fires,      // d_out
               float* __restrict__ out_int)    // d_out + B*T
{
    __shared__ float lds[3][R][LSTR];
    const int tid     = threadIdx.x;
    const int rowbase = blockIdx.x * R;

    const bool is_comp = (tid < 64);          // wave 0 (lanes 0-15 active)

    // stager decomposition: 256 lanes x 2 float4 per tile.
    // q = sid + 256*j -> r = q>>5 (0..15), c4 = q&31 (0..31); r1 = r0 + 8.
    const int sid = tid - 64;
    const int r0  = (sid >> 5) & 7;           // 0..7   (j=0)
    const int r1  = r0 + 8;                   // 8..15  (j=1)
    const int c4  = sid & 31;

    const float4* __restrict__ srcf4 = (const float4*)A;
    float4*       __restrict__ dstf4 = (float4*)fires;
    const size_t rowstr = Tn / 4;             // f4 per row

    // prologue: stage tile 0
    if (!is_comp){
        float4 a0 = srcf4[(size_t)(rowbase + r0) * rowstr + c4];
        float4 a1 = srcf4[(size_t)(rowbase + r1) * rowstr + c4];
        *(float4*)&lds[0][r0][4 * c4] = a0;
        *(float4*)&lds[0][r1][4 * c4] = a1;
    }
    float acc = (tid < R) ? integ[rowbase + tid] : 0.f;
    __syncthreads();

    int cur = 0;                              // buffer of tile k
    for (int k = 0; k < NT; ++k){
        const int nxt = (cur == 2) ? 0 : cur + 1;   // buffer of tile k+1
        const int prv = (cur == 0) ? 2 : cur - 1;   // buffer of tile k-1

        if (is_comp){
            if (tid < R){
                float4* rowp = (float4*)&lds[cur][tid][0];
                #pragma unroll
                for (int g = 0; g < C / 4; ++g){
                    float4 v = rowp[g];
                    float s0 = acc + v.x; acc = cif_fract(s0);
                    float s1 = acc + v.y; acc = cif_fract(s1);
                    float s2 = acc + v.z; acc = cif_fract(s2);
                    float s3 = acc + v.w; acc = cif_fract(s3);
                    rowp[g] = make_float4(s0, s1, s2, s3);   // fires in place
                }
            }
        } else {
            if (k > 0){   // store fires of tile k-1
                float4 f0 = *(const float4*)&lds[prv][r0][4 * c4];
                float4 f1 = *(const float4*)&lds[prv][r1][4 * c4];
                dstf4[(size_t)(rowbase + r0) * rowstr + (size_t)(k - 1) * (C / 4) + c4] = f0;
                dstf4[(size_t)(rowbase + r1) * rowstr + (size_t)(k - 1) * (C / 4) + c4] = f1;
            }
            if (k + 1 < NT){   // stage tile k+1
                float4 a0 = srcf4[(size_t)(rowbase + r0) * rowstr + (size_t)(k + 1) * (C / 4) + c4];
                float4 a1 = srcf4[(size_t)(rowbase + r1) * rowstr + (size_t)(k + 1) * (C / 4) + c4];
                *(float4*)&lds[nxt][r0][4 * c4] = a0;
                *(float4*)&lds[nxt][r1][4 * c4] = a1;
            }
        }
        __syncthreads();
        cur = nxt;
    }

    // epilogue: store fires of the last tile; write final accumulators
    if (!is_comp){
        const int prv = (cur == 0) ? 2 : cur - 1;
        float4 f0 = *(const float4*)&lds[prv][r0][4 * c4];
        float4 f1 = *(const float4*)&lds[prv][r1][4 * c4];
        dstf4[(size_t)(rowbase + r0) * rowstr + (size_t)(NT - 1) * (C / 4) + c4] = f0;
        dstf4[(size_t)(rowbase + r1) * rowstr + (size_t)(NT - 1) * (C / 4) + c4] = f1;
    }
    if (tid < R) out_int[rowbase + tid] = acc;
}

// ----------------------------- Launch --------------------------------------
extern "C" void kernel_launch(void* const* d_in, const int* in_sizes, int n_in,
                              void* d_out, int out_size, void* d_ws, size_t ws_size,
                              hipStream_t stream)
{
    const float* A     = (const float*)d_in[0];   // us_alphas [B][T]
    const float* integ = (const float*)d_in[1];   // integrate [B]
    float* out = (float*)d_out;                   // fires [B*T] ++ integrate_new [B]

    hipLaunchKernelGGL(cif_fused, dim3(NBLK), dim3(NTHR), 0, stream,
                       A, integ, out, out + (size_t)Bn * Tn);
}

// Round 5
// 242.986 us; speedup vs baseline: 2.5244x; 1.0347x over previous
//
#include <hip/hip_runtime.h>

// CIF (continuous integrate-and-fire), fused single pass, v3.
// Bit-exact vs reference: s = fl32(acc + a); fire = s; acc = fract(s)
// (exact for s in [0,2): Sterbenz).
//
// Structure: 256 blocks x 320 threads (5 waves), 16 rows per block (1 block/CU).
//   LDS tile: row-major [16 rows][128 cols + 4 pad] (row stride 528B; compute
//   reads/writes are 2-way bank-aliased = free; stager 4-way on b128 = cheap).
//   Ring of 3 buffers, one barrier per tile:
//     wave 0  : lane l (l<16) computes row l's 128-step chain. v3 change:
//               tile processed as 4 sub-blocks of 8 float4 held in REGISTERS,
//               next sub-block's 8 ds_read_b128 issued before computing the
//               current one -> LDS latency hidden under the VALU chain
//               (v2 serialized ~120cyc read latency into every 4 steps).
//     waves1-4: issue tile k+1 global loads FIRST, then store tile k-1 fires
//               (LDS->global, coalesced), then LDS-write tile k+1 (vmcnt wait
//               lands here, hidden under compute).
// Floors: per-lane chain 8192*8cyc = 27us; effective HBM traffic ~200MB
// (L3 absorbs ~half of A) -> ~32us. Target dispatch ~40-50us.

constexpr int Bn   = 4096;
constexpr int Tn   = 8192;
constexpr int R    = 16;          // rows (chains) per block
constexpr int C    = 128;         // cols per tile
constexpr int LSTR = C + 4;       // 132 floats = 528B row stride (16B aligned)
constexpr int NT   = Tn / C;      // 64 tiles
constexpr int NBLK = Bn / R;      // 256 blocks
constexpr int NTHR = 320;         // 5 waves
constexpr int SB   = 8;           // float4 per sub-block
constexpr int NSB  = (C / 4) / SB; // 4 sub-blocks per tile

__device__ __forceinline__ float cif_fract(float s){
#if __has_builtin(__builtin_amdgcn_fractf)
    return __builtin_amdgcn_fractf(s);   // v_fract_f32: s - floor(s), exact
#else
    return s - floorf(s);
#endif
}

__global__ __launch_bounds__(NTHR)
void cif_fused(const float* __restrict__ A,
               const float* __restrict__ integ,
               float* __restrict__ fires,      // d_out
               float* __restrict__ out_int)    // d_out + B*T
{
    __shared__ float lds[3][R][LSTR];
    const int tid     = threadIdx.x;
    const int rowbase = blockIdx.x * R;

    const bool is_comp = (tid < 64);          // wave 0 (lanes 0-15 active)

    // stager decomposition: 256 lanes x 2 float4 per tile.
    const int sid = tid - 64;
    const int r0  = (sid >> 5) & 7;           // 0..7   (j=0)
    const int r1  = r0 + 8;                   // 8..15  (j=1)
    const int c4  = sid & 31;

    const float4* __restrict__ srcf4 = (const float4*)A;
    float4*       __restrict__ dstf4 = (float4*)fires;
    const size_t rowstr = Tn / 4;             // f4 per row

    // prologue: stage tile 0
    if (!is_comp){
        float4 a0 = srcf4[(size_t)(rowbase + r0) * rowstr + c4];
        float4 a1 = srcf4[(size_t)(rowbase + r1) * rowstr + c4];
        *(float4*)&lds[0][r0][4 * c4] = a0;
        *(float4*)&lds[0][r1][4 * c4] = a1;
    }
    float acc = (tid < R) ? integ[rowbase + tid] : 0.f;
    __syncthreads();

    int cur = 0;                              // buffer of tile k
    for (int k = 0; k < NT; ++k){
        const int nxt = (cur == 2) ? 0 : cur + 1;   // buffer of tile k+1
        const int prv = (cur == 0) ? 2 : cur - 1;   // buffer of tile k-1

        if (is_comp){
            if (tid < R){
                float4* rowp = (float4*)&lds[cur][tid][0];
                float4 buf[SB];
                #pragma unroll
                for (int j = 0; j < SB; ++j) buf[j] = rowp[j];
                #pragma unroll
                for (int sb = 0; sb < NSB; ++sb){
                    float4 nbuf[SB];
                    if (sb + 1 < NSB){        // prefetch next sub-block
                        #pragma unroll
                        for (int j = 0; j < SB; ++j)
                            nbuf[j] = rowp[SB * (sb + 1) + j];
                    }
                    #pragma unroll
                    for (int j = 0; j < SB; ++j){
                        float4 v = buf[j];
                        float s0 = acc + v.x; acc = cif_fract(s0);
                        float s1 = acc + v.y; acc = cif_fract(s1);
                        float s2 = acc + v.z; acc = cif_fract(s2);
                        float s3 = acc + v.w; acc = cif_fract(s3);
                        rowp[SB * sb + j] = make_float4(s0, s1, s2, s3);
                    }
                    if (sb + 1 < NSB){
                        #pragma unroll
                        for (int j = 0; j < SB; ++j) buf[j] = nbuf[j];
                    }
                }
            }
        } else {
            // 1. issue next tile's global loads early (HBM latency hides here)
            float4 a0, a1;
            const bool pf = (k + 1 < NT);
            if (pf){
                a0 = srcf4[(size_t)(rowbase + r0) * rowstr + (size_t)(k + 1) * (C / 4) + c4];
                a1 = srcf4[(size_t)(rowbase + r1) * rowstr + (size_t)(k + 1) * (C / 4) + c4];
            }
            // 2. store fires of tile k-1
            if (k > 0){
                float4 f0 = *(const float4*)&lds[prv][r0][4 * c4];
                float4 f1 = *(const float4*)&lds[prv][r1][4 * c4];
                dstf4[(size_t)(rowbase + r0) * rowstr + (size_t)(k - 1) * (C / 4) + c4] = f0;
                dstf4[(size_t)(rowbase + r1) * rowstr + (size_t)(k - 1) * (C / 4) + c4] = f1;
            }
            // 3. LDS-write tile k+1 (vmcnt wait on the early loads lands here)
            if (pf){
                *(float4*)&lds[nxt][r0][4 * c4] = a0;
                *(float4*)&lds[nxt][r1][4 * c4] = a1;
            }
        }
        __syncthreads();
        cur = nxt;
    }

    // epilogue: store fires of the last tile; write final accumulators
    if (!is_comp){
        const int prv = (cur == 0) ? 2 : cur - 1;
        float4 f0 = *(const float4*)&lds[prv][r0][4 * c4];
        float4 f1 = *(const float4*)&lds[prv][r1][4 * c4];
        dstf4[(size_t)(rowbase + r0) * rowstr + (size_t)(NT - 1) * (C / 4) + c4] = f0;
        dstf4[(size_t)(rowbase + r1) * rowstr + (size_t)(NT - 1) * (C / 4) + c4] = f1;
    }
    if (tid < R) out_int[rowbase + tid] = acc;
}

// ----------------------------- Launch --------------------------------------
extern "C" void kernel_launch(void* const* d_in, const int* in_sizes, int n_in,
                              void* d_out, int out_size, void* d_ws, size_t ws_size,
                              hipStream_t stream)
{
    const float* A     = (const float*)d_in[0];   // us_alphas [B][T]
    const float* integ = (const float*)d_in[1];   // integrate [B]
    float* out = (float*)d_out;                   // fires [B*T] ++ integrate_new [B]

    hipLaunchKernelGGL(cif_fused, dim3(NBLK), dim3(NTHR), 0, stream,
                       A, integ, out, out + (size_t)Bn * Tn);
}